// Round 11
// baseline (390.878 us; speedup 1.0000x reference)
//
#include <hip/hip_runtime.h>

// DEQ split into two kernels.
//   K1 deq_loop: z* = relu^{(30)}(z Wz^T + inj), inj = x Ux^T + b.
//     Round-9 2n x 2m mapping (LDS amp 2x: per wave-iter 4 ds_read_b128 +
//     4 ds_write_b64, 16 MFMA), loop-only register peak ~120 unified
//     (awz 64 + inj 16 + acc 16 + bz 16 + addr) -> 4 waves/SIMD under
//     launch_bounds(256,4). Round 10 proved the decoder tail (awd 32 regs
//     live alongside awz) is what pushed the whole-kernel peak past 128 and
//     spilled (WRITE_SIZE 65->143 MB). So the decoder is amputated.
//     Final z (bf16, 128/row = 256 B) is staged IN THE OUT BUFFER (out row
//     footprint = 64 f32 = 256 B, exact match), coalesced 128B stores.
//   K2 deq_dec: out = z* Wd^T + bd, in place over the staged z. Safe: each
//     lane reads only its own row's z (B-frag row = l15 = D-store row) and
//     the stores depend on all loads. HBM-bound ~25us.
// Cross-round law (r7-r10): throughput ~ resident waves x MFMA/wave;
// T_iter ~2500-2800cy invariant. Target config = amp-2 traffic at 4
// waves/SIMD: matrix 1240cy vs LDS 1152cy per 4-block generation.

typedef __attribute__((ext_vector_type(8))) __bf16 bf16x8;
typedef __attribute__((ext_vector_type(4))) __bf16 bf16x4;
typedef __attribute__((ext_vector_type(4))) float  floatx4;

#define MFMA16(a, b, c) __builtin_amdgcn_mfma_f32_16x16x32_bf16((a), (b), (c), 0, 0, 0)

static constexpr int kBsz = 262144;
static constexpr int kTM  = 32;    // batch rows per K1 block
static constexpr int kLd  = 136;   // z LDS row stride (bf16 elems)

__device__ __forceinline__ bf16x8 cvt_bf16x8(float4 a, float4 b) {
  bf16x8 r;
  r[0] = (__bf16)a.x; r[1] = (__bf16)a.y; r[2] = (__bf16)a.z; r[3] = (__bf16)a.w;
  r[4] = (__bf16)b.x; r[5] = (__bf16)b.y; r[6] = (__bf16)b.z; r[7] = (__bf16)b.w;
  return r;
}

// ---------------- Kernel 1: fixed-point loop, writes z* (bf16) ----------------
__global__ void __launch_bounds__(256, 4) deq_loop(
    const float* __restrict__ x,    // [B,64]
    const float* __restrict__ Wz,   // [128,128]
    const float* __restrict__ Ux,   // [128,64]
    const float* __restrict__ bvec, // [128]
    const int*  __restrict__ n_iters_p,
    __bf16* __restrict__ zout)      // [B,128] staged in out buffer
{
  __shared__ __align__(16) __bf16 zl[2][kTM][kLd];   // 17408 B

  const int tid  = threadIdx.x;
  const int lane = tid & 63;
  const int wv   = tid >> 6;   // 0..3
  const int wn   = wv & 1;     // n-half: hid units [64*wn, 64*wn+64)
  const int wm   = wv >> 1;    // m-half: rows [16*wm, 16*wm+16)
  const int l15  = lane & 15;
  const int quad = lane >> 4;  // 0..3
  const int row0 = blockIdx.x * kTM;
  const int ml   = 16 * wm + l15;   // this wave's local m row
  const int iters = *n_iters_p;

  // ---- Wz as A-fragments (iteration-invariant, 64 regs in acc file) ----
  // A[n][k]: n = 64*wn + 16*nt + l15, k = 32*ks + 8*quad + j
  bf16x8 awz[4][4];
#pragma unroll
  for (int nt = 0; nt < 4; ++nt) {
    const int n = 64 * wn + 16 * nt + l15;
#pragma unroll
    for (int ks = 0; ks < 4; ++ks) {
      const float4* p = (const float4*)(Wz + n * 128 + 32 * ks + 8 * quad);
      awz[nt][ks] = cvt_bf16x8(p[0], p[1]);
    }
  }

  // ---- inj^T in C/D layout: inj[nt], reg i -> n = 64wn+16nt+4quad+i ----
  floatx4 inj[4];
#pragma unroll
  for (int nt = 0; nt < 4; ++nt) {
    const float4 bv = *(const float4*)(bvec + 64 * wn + 16 * nt + 4 * quad);
    floatx4 v = {bv.x, bv.y, bv.z, bv.w};
    inj[nt] = v;
  }
  {
    // x^T as B-frag for this wave's m rows (K=64 -> 2 k-steps)
    bf16x8 bx[2];
#pragma unroll
    for (int ks = 0; ks < 2; ++ks) {
      const float4* p = (const float4*)(x + (size_t)(row0 + ml) * 64 + 32 * ks + 8 * quad);
      bx[ks] = cvt_bf16x8(p[0], p[1]);
    }
#pragma unroll
    for (int nt = 0; nt < 4; ++nt) {
      const int n = 64 * wn + 16 * nt + l15;
#pragma unroll
      for (int ks = 0; ks < 2; ++ks) {
        const float4* p = (const float4*)(Ux + n * 64 + 32 * ks + 8 * quad);
        const bf16x8 a = cvt_bf16x8(p[0], p[1]);
        inj[nt] = MFMA16(a, bx[ks], inj[nt]);
      }
    }
  }

  // ---- z1 = relu(inj) (z0 = 0) -> buffer 0, packed b64 writes ----
#pragma unroll
  for (int nt = 0; nt < 4; ++nt) {
    bf16x4 z4;
#pragma unroll
    for (int i = 0; i < 4; ++i) z4[i] = (__bf16)fmaxf(inj[nt][i], 0.0f);
    *(bf16x4*)&zl[0][ml][64 * wn + 16 * nt + 4 * quad] = z4;
  }

  // ---- fixed-point loop: 1 barrier per iteration (double buffer) ----
  int pb = 0;
  for (int t = 0; t < iters - 1; ++t) {
    __syncthreads();
    // full-k B-frags for this wave's m rows: 4 x ds_read_b128, one burst
    bf16x8 bz[4];
#pragma unroll
    for (int ks = 0; ks < 4; ++ks)
      bz[ks] = *(const bf16x8*)&zl[pb][ml][32 * ks + 8 * quad];
    const int nb = pb ^ 1;
#pragma unroll
    for (int nt = 0; nt < 4; ++nt) {
      floatx4 acc = inj[nt];
#pragma unroll
      for (int ks = 0; ks < 4; ++ks)
        acc = MFMA16(awz[nt][ks], bz[ks], acc);
      bf16x4 z4;
#pragma unroll
      for (int i = 0; i < 4; ++i) z4[i] = (__bf16)fmaxf(acc[i], 0.0f);
      // reg axis i is consecutive n -> one ds_write_b64
      *(bf16x4*)&zl[nb][ml][64 * wn + 16 * nt + 4 * quad] = z4;
    }
    pb = nb;
  }
  __syncthreads();

  // ---- coalesced z* write: 8 threads x 16 bf16 per row, 128B/row bursts ----
  const int r = tid >> 3;            // 0..31
  const int c = (tid & 7) * 16;      // 0..112
  const bf16x8 zlo = *(const bf16x8*)&zl[pb][r][c];
  const bf16x8 zhi = *(const bf16x8*)&zl[pb][r][c + 8];
  *(bf16x8*)&zout[(size_t)(row0 + r) * 128 + c] = zlo;
  *(bf16x8*)&zout[(size_t)(row0 + r) * 128 + c + 8] = zhi;
}

// ---------------- Kernel 2: decoder, in place over staged z ----------------
__global__ void __launch_bounds__(256) deq_dec(
    const float* __restrict__ Wd,   // [64,128]
    const float* __restrict__ bd,   // [64]
    float* __restrict__ out)        // [B,64]; rows currently hold z* as bf16
{
  const int tid  = threadIdx.x;
  const int lane = tid & 63;
  const int wv   = tid >> 6;   // 0..3 -> rows [16*wv, 16*wv+16)
  const int l15  = lane & 15;
  const int quad = lane >> 4;  // 0..3
  const int row  = blockIdx.x * 64 + 16 * wv + l15;  // this lane's batch row
  const __bf16* zin = (const __bf16*)out;

  // z B-frags: B[k][m=row], k = 32ks+8quad+j  (lane reads ONLY its own row)
  bf16x8 bz[4];
#pragma unroll
  for (int ks = 0; ks < 4; ++ks)
    bz[ks] = *(const bf16x8*)&zin[(size_t)row * 128 + 32 * ks + 8 * quad];

  // Wd as A-frags: full o=64 (4 tiles), o = 16*ot + l15
#pragma unroll
  for (int ot = 0; ot < 4; ++ot) {
    const int o = 16 * ot + l15;
    const float4 bv = *(const float4*)(bd + 16 * ot + 4 * quad);
    floatx4 acc = {bv.x, bv.y, bv.z, bv.w};
#pragma unroll
    for (int ks = 0; ks < 4; ++ks) {
      const float4* p = (const float4*)(Wd + o * 128 + 32 * ks + 8 * quad);
      const bf16x8 a = cvt_bf16x8(p[0], p[1]);
      acc = MFMA16(a, bz[ks], acc);
    }
    // D: lane (q,l) holds out[row=l15-row][o=16ot+4q+i], i consecutive
    float4 ov;
    ov.x = acc[0]; ov.y = acc[1]; ov.z = acc[2]; ov.w = acc[3];
    *(float4*)(out + (size_t)row * 64 + 16 * ot + 4 * quad) = ov;
  }
}

extern "C" void kernel_launch(void* const* d_in, const int* in_sizes, int n_in,
                              void* d_out, int out_size, void* d_ws, size_t ws_size,
                              hipStream_t stream) {
  const float* x  = (const float*)d_in[0];
  const float* Wz = (const float*)d_in[1];
  const float* Ux = (const float*)d_in[2];
  const float* b  = (const float*)d_in[3];
  const float* Wd = (const float*)d_in[4];
  const float* bd = (const float*)d_in[5];
  const int* n_it = (const int*)d_in[6];
  float* outp = (float*)d_out;
  (void)in_sizes; (void)n_in; (void)d_ws; (void)ws_size; (void)out_size;

  dim3 g1(kBsz / kTM);   // 8192 blocks of 256
  deq_loop<<<g1, 256, 0, stream>>>(x, Wz, Ux, b, n_it, (__bf16*)outp);
  dim3 g2(kBsz / 64);    // 4096 blocks of 256
  deq_dec<<<g2, 256, 0, stream>>>(Wd, bd, outp);
}

// Round 12
// 370.121 us; speedup vs baseline: 1.0561x; 1.0561x over previous
//
#include <hip/hip_runtime.h>

// DEQ fused: out = relu^{(30)}(z Wz^T + inj) @ Wd^T + bd, inj = x Ux^T + b
//
// Round-12: fused round-9 (2n x 2m mapping, amp-2 LDS traffic) minus 16
// registers, to reach 4 waves/SIMD (round-11 measured the loop live set at
// ~144 unified: 64 VGPR + awz 64 + inj 16 AGPR -> 3.4 waves/SIMD).
//   - inj: 16 f32 -> 8 u32 packed bf16 pairs; unpacked per iter (16 VALU).
//     Precision: +<=0.002/elem rounding, resolvent-amplified ~<=0.015;
//     current absmax 0.0078, threshold 0.0337.
//   - precomputed LDS element offsets rdo/wro; ks-paired reads (bz live 8).
//   - decoder FUSED (round-11: a second dispatch costs ~50-60us bench;
//     r9 proved the fused tail reuses awz space without raising the peak).
// Target regime (cross-round ledger r8-r11): amp-2 traffic AT 16.3 waves/CU
// -> LDS ~50%, matrix 55-60% -> ~230us. r8 (252us) sits at its LDS ceiling;
// r9/r11 (322/256) had LDS slack but only 13.6 waves.

typedef __attribute__((ext_vector_type(8))) __bf16 bf16x8;
typedef __attribute__((ext_vector_type(4))) __bf16 bf16x4;
typedef __attribute__((ext_vector_type(2))) __bf16 bf16x2;
typedef __attribute__((ext_vector_type(4))) float  floatx4;

#define MFMA16(a, b, c) __builtin_amdgcn_mfma_f32_16x16x32_bf16((a), (b), (c), 0, 0, 0)

static constexpr int kBsz = 262144;
static constexpr int kTM  = 32;    // batch rows per block
static constexpr int kLd  = 136;   // z LDS row stride (bf16 elems)

__device__ __forceinline__ bf16x8 cvt_bf16x8(float4 a, float4 b) {
  bf16x8 r;
  r[0] = (__bf16)a.x; r[1] = (__bf16)a.y; r[2] = (__bf16)a.z; r[3] = (__bf16)a.w;
  r[4] = (__bf16)b.x; r[5] = (__bf16)b.y; r[6] = (__bf16)b.z; r[7] = (__bf16)b.w;
  return r;
}

__device__ __forceinline__ unsigned pack2(float a, float b) {
  union { bf16x2 h; unsigned u; } x;
  x.h[0] = (__bf16)a;
  x.h[1] = (__bf16)b;
  return x.u;
}

__global__ void __launch_bounds__(256, 4) deq_fused(
    const float* __restrict__ x,    // [B,64]
    const float* __restrict__ Wz,   // [128,128]
    const float* __restrict__ Ux,   // [128,64]
    const float* __restrict__ bvec, // [128]
    const float* __restrict__ Wd,   // [64,128]
    const float* __restrict__ bd,   // [64]
    const int*  __restrict__ n_iters_p,
    float* __restrict__ out)        // [B,64]
{
  // double-buffered z tile, row-major [m][n], stride 136 bf16 = 272 B
  __shared__ __align__(16) __bf16 zl[2][kTM][kLd];   // 17408 B

  const int tid  = threadIdx.x;
  const int lane = tid & 63;
  const int wv   = tid >> 6;   // 0..3
  const int wn   = wv & 1;     // n-half: hid units [64*wn, 64*wn+64)
  const int wm   = wv >> 1;    // m-half: rows [16*wm, 16*wm+16)
  const int l15  = lane & 15;
  const int quad = lane >> 4;  // 0..3
  const int row0 = blockIdx.x * kTM;
  const int ml   = 16 * wm + l15;   // this wave's local m row
  const int iters = *n_iters_p;

  // per-lane LDS element offsets (buffer-relative)
  const int rdo = ml * kLd + 8 * quad;             // + 32*ks
  const int wro = ml * kLd + 64 * wn + 4 * quad;   // + 16*nt

  // ---- Wz as A-fragments (iteration-invariant, 64 regs in acc file) ----
  // A[n][k]: n = 64*wn + 16*nt + l15, k = 32*ks + 8*quad + j
  bf16x8 awz[4][4];
#pragma unroll
  for (int nt = 0; nt < 4; ++nt) {
    const int n = 64 * wn + 16 * nt + l15;
#pragma unroll
    for (int ks = 0; ks < 4; ++ks) {
      const float4* p = (const float4*)(Wz + n * 128 + 32 * ks + 8 * quad);
      awz[nt][ks] = cvt_bf16x8(p[0], p[1]);
    }
  }

  // ---- inj prologue (f32 via MFMA), then packed to 8 u32 bf16 pairs ----
  unsigned injp[8];
  {
    floatx4 inj[4];
#pragma unroll
    for (int nt = 0; nt < 4; ++nt) {
      const float4 bv = *(const float4*)(bvec + 64 * wn + 16 * nt + 4 * quad);
      floatx4 v = {bv.x, bv.y, bv.z, bv.w};
      inj[nt] = v;
    }
    // x^T as B-frag for this wave's m rows (K=64 -> 2 k-steps)
    bf16x8 bx[2];
#pragma unroll
    for (int ks = 0; ks < 2; ++ks) {
      const float4* p = (const float4*)(x + (size_t)(row0 + ml) * 64 + 32 * ks + 8 * quad);
      bx[ks] = cvt_bf16x8(p[0], p[1]);
    }
#pragma unroll
    for (int nt = 0; nt < 4; ++nt) {
      const int n = 64 * wn + 16 * nt + l15;
#pragma unroll
      for (int ks = 0; ks < 2; ++ks) {
        const float4* p = (const float4*)(Ux + n * 64 + 32 * ks + 8 * quad);
        const bf16x8 a = cvt_bf16x8(p[0], p[1]);
        inj[nt] = MFMA16(a, bx[ks], inj[nt]);
      }
    }
    // z1 = relu(inj) -> buffer 0 (inj still f32 here)
#pragma unroll
    for (int nt = 0; nt < 4; ++nt) {
      bf16x4 z4;
#pragma unroll
      for (int i = 0; i < 4; ++i) z4[i] = (__bf16)fmaxf(inj[nt][i], 0.0f);
      *(bf16x4*)&zl[0][0][wro + 16 * nt];
      *(bf16x4*)&zl[0][0][wro + 16 * nt] = z4;
    }
    // pack inj (loop-resident form: 8 regs instead of 16)
#pragma unroll
    for (int nt = 0; nt < 4; ++nt) {
      injp[2 * nt]     = pack2(inj[nt][0], inj[nt][1]);
      injp[2 * nt + 1] = pack2(inj[nt][2], inj[nt][3]);
    }
  }

  // ---- fixed-point loop: 1 barrier per iteration (double buffer) ----
  int pb = 0;
  for (int t = 0; t < iters - 1; ++t) {
    __syncthreads();
    const __bf16* src = &zl[pb][0][0];
    __bf16* dst = &zl[pb ^ 1][0][0];
    // acc init from packed inj: bf16 -> f32 is a shift / mask
    floatx4 acc[4];
#pragma unroll
    for (int nt = 0; nt < 4; ++nt) {
      const unsigned u0 = injp[2 * nt];
      const unsigned u1 = injp[2 * nt + 1];
      acc[nt][0] = __uint_as_float(u0 << 16);
      acc[nt][1] = __uint_as_float(u0 & 0xffff0000u);
      acc[nt][2] = __uint_as_float(u1 << 16);
      acc[nt][3] = __uint_as_float(u1 & 0xffff0000u);
    }
    // ks-paired reads (bz live = 8 regs) + MFMA
    {
      const bf16x8 b0 = *(const bf16x8*)&src[rdo];
      const bf16x8 b1 = *(const bf16x8*)&src[rdo + 32];
#pragma unroll
      for (int nt = 0; nt < 4; ++nt) acc[nt] = MFMA16(awz[nt][0], b0, acc[nt]);
#pragma unroll
      for (int nt = 0; nt < 4; ++nt) acc[nt] = MFMA16(awz[nt][1], b1, acc[nt]);
    }
    {
      const bf16x8 b2 = *(const bf16x8*)&src[rdo + 64];
      const bf16x8 b3 = *(const bf16x8*)&src[rdo + 96];
#pragma unroll
      for (int nt = 0; nt < 4; ++nt) acc[nt] = MFMA16(awz[nt][2], b2, acc[nt]);
#pragma unroll
      for (int nt = 0; nt < 4; ++nt) acc[nt] = MFMA16(awz[nt][3], b3, acc[nt]);
    }
    // relu + pack + packed b64 writes (reg axis i = consecutive n)
#pragma unroll
    for (int nt = 0; nt < 4; ++nt) {
      bf16x4 z4;
#pragma unroll
      for (int i = 0; i < 4; ++i) z4[i] = (__bf16)fmaxf(acc[nt][i], 0.0f);
      *(bf16x4*)&dst[wro + 16 * nt] = z4;
    }
    pb ^= 1;
  }
  __syncthreads();

  // ---- decoder (fused; awz dead, awd reuses its space) ----
  const __bf16* zf = &zl[pb][0][0];
  bf16x8 bz[4];
#pragma unroll
  for (int ks = 0; ks < 4; ++ks)
    bz[ks] = *(const bf16x8*)&zf[rdo + 32 * ks];
#pragma unroll
  for (int ot = 0; ot < 2; ++ot) {
    const int o = 32 * wn + 16 * ot + l15;
    const float4 bv = *(const float4*)(bd + 32 * wn + 16 * ot + 4 * quad);
    floatx4 acc = {bv.x, bv.y, bv.z, bv.w};
#pragma unroll
    for (int ks = 0; ks < 4; ++ks) {
      const float4* p = (const float4*)(Wd + o * 128 + 32 * ks + 8 * quad);
      const bf16x8 a = cvt_bf16x8(p[0], p[1]);
      acc = MFMA16(a, bz[ks], acc);
    }
    // reg i -> consecutive o: one dwordx4 global store
    float4 ov;
    ov.x = acc[0]; ov.y = acc[1]; ov.z = acc[2]; ov.w = acc[3];
    *(float4*)(out + (size_t)(row0 + ml) * 64 + 32 * wn + 16 * ot + 4 * quad) = ov;
  }
}

extern "C" void kernel_launch(void* const* d_in, const int* in_sizes, int n_in,
                              void* d_out, int out_size, void* d_ws, size_t ws_size,
                              hipStream_t stream) {
  const float* x  = (const float*)d_in[0];
  const float* Wz = (const float*)d_in[1];
  const float* Ux = (const float*)d_in[2];
  const float* b  = (const float*)d_in[3];
  const float* Wd = (const float*)d_in[4];
  const float* bd = (const float*)d_in[5];
  const int* n_it = (const int*)d_in[6];
  float* outp = (float*)d_out;
  (void)in_sizes; (void)n_in; (void)d_ws; (void)ws_size; (void)out_size;

  dim3 grid(kBsz / kTM);  // 8192 blocks of 256 threads
  deq_fused<<<grid, 256, 0, stream>>>(x, Wz, Ux, b, Wd, bd, n_it, outp);
}